// Round 3
// baseline (1008.840 us; speedup 1.0000x reference)
//
#include <hip/hip_runtime.h>

// Problem constants
#define NN   65536      // N nodes
#define NE   524288     // E edges
#define EPG  8192       // edges per graph

// Output float offsets in d_out (total 10111552 floats)
#define O1 7913472      // ei_new (2*E)
#define O2 8962048      // ea_new (E)
#define O3 9486336      // batch_out (30912)
#define O4 9517248      // perm (30912)
#define O5 9548160      // score_perm (30912)
#define O6 9579072      // sentence_scores (4096)
#define O7 9583168      // sentence_batch (4096)
#define O8 9587264      // keep (E)

// Scratch placement (float offsets), lifetime-verified:
//  ybuf   [0, 8388608)        dies after last k_gemm
//  packed [8388608, 8912896)  dies after k_score_edges (k_edges overwrites O1 span)
//  coef   [8912896, 9437184)  dies after k_score_edges (k_edges overwrites O2 span)
//  deg    [9437184, 9502720)  dies after k_score_edges (k_topk writes O3 span)
//  z      [9502720, 9568256)  dies after k_score_edges
//  score  [65536, 131072)     written after ybuf dies; dies after k_topk (k_xout last)
//  mask   ints [0, 65536)     written after ybuf dies; read k_edges; k_xout overwrites last
#define PACK_OFF 8388608
#define COEF_OFF 8912896
#define DEG_OFF  9437184
#define Z_OFF    9502720
#define SCORE_OFF 65536

__device__ __forceinline__ unsigned monof(float f) {
  unsigned u = __float_as_uint(f);
  return (u & 0x80000000u) ? ~u : (u | 0x80000000u);  // ascending monotone map
}

__global__ void k_init(float* __restrict__ deg, float* __restrict__ z) {
  int n = blockIdx.x * 256 + threadIdx.x;
  if (n < NN) { deg[n] = 1.0f; z[n] = 0.0f; }
}

__global__ void k_deg(const int* __restrict__ ei, const float* __restrict__ w,
                      float* __restrict__ deg) {
  int e = blockIdx.x * 256 + threadIdx.x;
  if (e < NE) unsafeAtomicAdd(&deg[ei[NE + e]], w[e]);
}

__global__ void k_dinv(float* __restrict__ deg) {
  int n = blockIdx.x * 256 + threadIdx.x;
  if (n < NN) { float d = deg[n]; deg[n] = d > 0.0f ? 1.0f / sqrtf(d) : 0.0f; }
}

// packed[e] = (LOCAL_row << 16) | local_col ; coef[e] = w[e]*dinv[row]
__global__ void k_pack(const int* __restrict__ ei, const float* __restrict__ w,
                       const float* __restrict__ dinv,
                       unsigned* __restrict__ packed, float* __restrict__ coef) {
  int e = blockIdx.x * 256 + threadIdx.x;
  if (e < NE) {
    int r = ei[e];
    packed[e] = ((unsigned)(r & 1023) << 16) | (unsigned)(ei[NE + e] & 1023);
    coef[e] = w[e] * dinv[r];
  }
}

// Aggregate x over normalized adjacency into ybuf (chunk of 32 graphs).
// One block = (graph g, 8-column chunk cc). x-slice staged in LDS once
// (sequential reads), edge loop reads x from LDS (short latency chain).
// Stride-9 rows spread random-row access over all 32 banks.
__global__ __launch_bounds__(256, 2) void k_aggx(const float* __restrict__ x,
    const unsigned* __restrict__ packed, const float* __restrict__ coef,
    const float* __restrict__ dinv, float* __restrict__ ybuf, int gbase) {
  __shared__ float xs[1024 * 9];   // 36 KB: xs[n*9+j] = x[node n][c0+j]
  __shared__ float acc[1024 * 9];  // 36 KB
  int bid = blockIdx.x;
  int g  = bid & 31;               // all 32 col-chunks of g land on XCD g%8
  int cc = bid >> 5;               // 32 chunks of 8 columns
  int gg = gbase + g;
  int c0 = cc * 8;
  int t = threadIdx.x;
  int nbase = gg << 10;
  // Stage x-slice + self-loop init, 4 groups of 8 pipelined loads
#pragma unroll
  for (int sg = 0; sg < 4; ++sg) {
    float v[8], dv[8];
#pragma unroll
    for (int u = 0; u < 8; ++u) {
      int i = t + (sg * 8 + u) * 256;
      v[u] = x[(nbase + (i >> 3)) * 256 + c0 + (i & 7)];
    }
#pragma unroll
    for (int u = 0; u < 8; ++u) {
      int i = t + (sg * 8 + u) * 256;
      dv[u] = dinv[nbase + (i >> 3)];
    }
#pragma unroll
    for (int u = 0; u < 8; ++u) {
      int i = t + (sg * 8 + u) * 256;
      int n = i >> 3, jj = i & 7;
      xs[n * 9 + jj] = v[u];
      acc[n * 9 + jj] = dv[u] * v[u];
    }
  }
  __syncthreads();
  int j = t & 7, slot = t >> 3;             // 32 groups of 8 lanes
  int ebase = gg * EPG + slot * 256;        // contiguous 256 edges per group
  for (int it = 0; it < 32; ++it) {
    int base = ebase + it * 8;
    unsigned pk[8]; float cf[8], xv[8];
#pragma unroll
    for (int u = 0; u < 8; ++u) pk[u] = packed[base + u];
#pragma unroll
    for (int u = 0; u < 8; ++u) cf[u] = coef[base + u];
#pragma unroll
    for (int u = 0; u < 8; ++u) xv[u] = xs[(pk[u] >> 16) * 9 + j];
#pragma unroll
    for (int u = 0; u < 8; ++u)
      atomicAdd(&acc[(pk[u] & 1023) * 9 + j], cf[u] * xv[u]);
  }
  __syncthreads();
  for (int s = 0; s < 32; ++s) {
    int i = t + s * 256;
    int n = i >> 3;
    ybuf[((g << 10) + n) * 256 + c0 + (i & 7)] = dinv[nbase + n] * acc[n * 9 + (i & 7)];
  }
}

// fp32 GEMM y(32768x256) @ W1(256x512), fused +b1 -> LeakyReLU -> dot W2 -> atomic z
// BM=64, BN=128, BK=32, 256 threads, acc 4x8 per thread.
__global__ __launch_bounds__(256) void k_gemm(const float* __restrict__ ybuf,
    const float* __restrict__ W1, const float* __restrict__ b1,
    const float* __restrict__ W2, float* __restrict__ z, int node_base) {
  __shared__ float As[32][68];    // [k][row], padded
  __shared__ float Bs[32][132];   // [k][col], padded
  int bx = blockIdx.x & 3;        // 4 col-blocks of 128
  int by = blockIdx.x >> 2;       // 512 row-blocks of 64
  int t = threadIdx.x;
  int tx = t & 15, ty = t >> 4;
  int row0 = by * 64;
  float acc[4][8] = {};
  for (int kt = 0; kt < 256; kt += 32) {
    __syncthreads();
#pragma unroll
    for (int s = 0; s < 8; ++s) {         // A: 64x32
      int i = t + s * 256;
      As[i & 31][i >> 5] = ybuf[(row0 + (i >> 5)) * 256 + kt + (i & 31)];
    }
#pragma unroll
    for (int s = 0; s < 16; ++s) {        // B: 32x128
      int i = t + s * 256;
      Bs[i >> 7][i & 127] = W1[(kt + (i >> 7)) * 512 + bx * 128 + (i & 127)];
    }
    __syncthreads();
#pragma unroll
    for (int kk = 0; kk < 32; ++kk) {
      float4 a4  = *(const float4*)&As[kk][ty * 4];
      float4 b4a = *(const float4*)&Bs[kk][tx * 4];        // stride-4: 2-way, free
      float4 b4b = *(const float4*)&Bs[kk][tx * 4 + 64];
      float a[4]  = {a4.x, a4.y, a4.z, a4.w};
      float bb[8] = {b4a.x, b4a.y, b4a.z, b4a.w, b4b.x, b4b.y, b4b.z, b4b.w};
#pragma unroll
      for (int r = 0; r < 4; ++r)
#pragma unroll
        for (int c = 0; c < 8; ++c)
          acc[r][c] += a[r] * bb[c];
    }
  }
  // epilogue: +b1, LeakyReLU, dot W2, reduce over tx, atomic into z
  int ca = bx * 128 + tx * 4, cb = ca + 64;
  float b1v[8], w2v[8];
#pragma unroll
  for (int c = 0; c < 8; ++c) {
    int col = (c < 4) ? ca + c : cb + (c - 4);
    b1v[c] = b1[col]; w2v[c] = W2[col];
  }
  float p[4] = {};
#pragma unroll
  for (int r = 0; r < 4; ++r)
#pragma unroll
    for (int c = 0; c < 8; ++c) {
      float v = acc[r][c] + b1v[c];
      v = v > 0.0f ? v : 0.01f * v;
      p[r] += v * w2v[c];
    }
#pragma unroll
  for (int o = 8; o > 0; o >>= 1)
#pragma unroll
    for (int r = 0; r < 4; ++r)
      p[r] += __shfl_xor(p[r], o, 16);
  if (tx == 0) {
    int node = node_base + row0 + ty * 4;
#pragma unroll
    for (int r = 0; r < 4; ++r)
      unsafeAtomicAdd(&z[node + r], p[r]);
  }
}

__global__ void k_mask_init(int* __restrict__ mask) {
  int n = blockIdx.x * 256 + threadIdx.x;
  if (n < NN) mask[n] = -1;
}

__global__ void k_score_init(const float* __restrict__ dinv, const float* __restrict__ z,
                             const float* __restrict__ b2, float* __restrict__ score) {
  int n = blockIdx.x * 256 + threadIdx.x;
  if (n < NN) score[n] = b2[0] + dinv[n] * dinv[n] * z[n];
}

__global__ void k_score_edges(const unsigned* __restrict__ packed,
                              const float* __restrict__ coef,
                              const float* __restrict__ dinv, const float* __restrict__ z,
                              float* __restrict__ score) {
  int e = blockIdx.x * 256 + threadIdx.x;
  if (e < NE) {
    unsigned pk = packed[e];
    int gb = (e >> 13) << 10;
    int r = gb | (pk >> 16);
    int c = gb | (pk & 1023);
    unsafeAtomicAdd(&score[c], coef[e] * dinv[c] * z[r]);
  }
}

__device__ void bitonic(unsigned long long* keys, int n, int t, int nt) {
  for (int k = 2; k <= n; k <<= 1)
    for (int jj = k >> 1; jj > 0; jj >>= 1) {
      __syncthreads();
      for (int i = t; i < n; i += nt) {
        int ixj = i ^ jj;
        if (ixj > i) {
          unsigned long long a = keys[i], c = keys[ixj];
          bool up = ((i & k) == 0);
          if ((a > c) == up) { keys[i] = c; keys[ixj] = a; }
        }
      }
    }
  __syncthreads();
}

// One block per graph: sentence top-3 (of 64) + other top-480 (of 960),
// lax.top_k order: value desc, index asc.
__global__ __launch_bounds__(256) void k_topk(const float* __restrict__ score,
                                              int* __restrict__ mask,
                                              float* __restrict__ out) {
  __shared__ unsigned long long keys[1024];
  int b = blockIdx.x, t = threadIdx.x;
  int base = b << 10;
  if (t < 64) {
    float v = score[base + t];
    keys[t] = ((unsigned long long)(~monof(v)) << 32) | (unsigned)t;
    out[O6 + b * 64 + t] = v;            // sentence_scores
    out[O7 + b * 64 + t] = (float)b;     // sentence_batch
  }
  __syncthreads();
  bitonic(keys, 64, t, 256);
  if (t < 3) {
    int idx = (int)(keys[t] & 0xFFFFFFFFull);
    int node = base + idx;
    int pos = b * 3 + t;
    mask[node] = pos;
    out[O4 + pos] = (float)node;
    out[O5 + pos] = score[node];
    out[O3 + pos] = (float)b;
  }
  __syncthreads();
  for (int i = t; i < 1024; i += 256) {
    if (i < 960) {
      float v = score[base + 64 + i];
      keys[i] = ((unsigned long long)(~monof(v)) << 32) | (unsigned)i;
    } else {
      keys[i] = 0xFFFFFFFFFFFFFFFFull;   // pad sorts last
    }
  }
  __syncthreads();
  bitonic(keys, 1024, t, 256);
  for (int r = t; r < 480; r += 256) {
    int idx = (int)(keys[r] & 0xFFFFFFFFull);
    int node = base + 64 + idx;
    int pos = 192 + b * 480 + r;
    mask[node] = pos;
    out[O4 + pos] = (float)node;
    out[O5 + pos] = score[node];
    out[O3 + pos] = (float)b;
  }
}

__global__ void k_edges(const int* __restrict__ ei, const float* __restrict__ w,
                        const int* __restrict__ mask, float* __restrict__ out) {
  int e = blockIdx.x * 256 + threadIdx.x;
  if (e >= NE) return;
  int nr = mask[ei[e]];
  int nc = mask[ei[NE + e]];
  bool keep = (nr >= 0) && (nc >= 0);
  out[O1 + e]      = keep ? (float)nr : -1.0f;
  out[O1 + NE + e] = keep ? (float)nc : -1.0f;
  out[O2 + e]      = keep ? w[e] : 0.0f;
  out[O8 + e]      = keep ? 1.0f : 0.0f;
}

__global__ void k_xout(const float* __restrict__ x, const float* __restrict__ permF,
                       const float* __restrict__ scoreP, float* __restrict__ out) {
  int i = blockIdx.x;                 // 30912 rows
  int node = (int)permF[i];
  float s = scoreP[i];
  const float4* xr = (const float4*)&x[node * 256];
  float4* o = (float4*)&out[i * 256];
  float4 v = xr[threadIdx.x];
  o[threadIdx.x] = make_float4(v.x * s, v.y * s, v.z * s, v.w * s);
}

extern "C" void kernel_launch(void* const* d_in, const int* in_sizes, int n_in,
                              void* d_out, int out_size, void* d_ws, size_t ws_size,
                              hipStream_t stream) {
  (void)in_sizes; (void)n_in; (void)out_size; (void)d_ws; (void)ws_size;
  const float* x  = (const float*)d_in[0];
  const int*   ei = (const int*)d_in[1];
  const float* w  = (const float*)d_in[2];
  const float* W1 = (const float*)d_in[4];
  const float* b1 = (const float*)d_in[5];
  const float* W2 = (const float*)d_in[6];
  const float* b2 = (const float*)d_in[7];
  float* out    = (float*)d_out;
  float* ybuf   = out;
  unsigned* packed = (unsigned*)(out + PACK_OFF);
  float* coef   = out + COEF_OFF;
  float* deg    = out + DEG_OFF;      // becomes dinv in-place
  float* z      = out + Z_OFF;
  float* score  = out + SCORE_OFF;
  int*   mask   = (int*)d_out;        // ints [0,65536), after ybuf dies

  k_init<<<256, 256, 0, stream>>>(deg, z);
  k_deg<<<2048, 256, 0, stream>>>(ei, w, deg);
  k_dinv<<<256, 256, 0, stream>>>(deg);
  k_pack<<<2048, 256, 0, stream>>>(ei, w, deg, packed, coef);
  for (int ch = 0; ch < 2; ++ch) {
    k_aggx<<<1024, 256, 0, stream>>>(x, packed, coef, deg, ybuf, ch * 32);
    k_gemm<<<2048, 256, 0, stream>>>(ybuf, W1, b1, W2, z, ch * 32768);
  }
  k_mask_init<<<256, 256, 0, stream>>>(mask);
  k_score_init<<<256, 256, 0, stream>>>(deg, z, b2, score);
  k_score_edges<<<2048, 256, 0, stream>>>(packed, coef, deg, z, score);
  k_topk<<<64, 256, 0, stream>>>(score, mask, out);
  k_edges<<<2048, 256, 0, stream>>>(ei, w, mask, out);
  k_xout<<<30912, 64, 0, stream>>>(x, out + O4, out + O5, out);
}

// Round 4
// 539.252 us; speedup vs baseline: 1.8708x; 1.8708x over previous
//
#include <hip/hip_runtime.h>

// Problem constants
#define NN   65536      // N nodes
#define NE   524288     // E edges
#define EPG  8192       // edges per graph

// Output float offsets in d_out (total 10111552 floats)
#define O1 7913472      // ei_new (2*E)
#define O2 8962048      // ea_new (E)
#define O3 9486336      // batch_out (30912)
#define O4 9517248      // perm (30912)
#define O5 9548160      // score_perm (30912)
#define O6 9579072      // sentence_scores (4096)
#define O7 9583168      // sentence_batch (4096)
#define O8 9587264      // keep (E)

// Scratch placement (float offsets), lifetime-verified:
//  ybuf   [0, 8388608)         dies after last k_gemm (k_edges writes O1 later)
//  csr    [8388608, 9437184)   u64[524288]; dies after k_score (before k_edges O1/O2)
//  dinv   [9437184, 9502720)   dies after k_score (k_topk writes O3.. later)
//  z      [9502720, 9568256)   dies after k_score
//  cnt    [9568256, 9633792)   dies after k_prefix (O8 written by k_edges later)
//  rstart [9633792, 9699329)   u32[65537]; dies after k_score
//  cursor [9699344, 9764880)   dies after k_scatter
//  wsum   [9764880, 9830416)   dies after k_prefix
//  score  [65536, 131072)      written after ybuf dies; dies after k_topk (k_xout last)
//  mask   ints [0, 65536)      written after ybuf dies; read k_edges; k_xout overwrites last
#define CSR_OFF    8388608
#define DINV_OFF   9437184
#define Z_OFF      9502720
#define CNT_OFF    9568256
#define RSTART_OFF 9633792
#define CURSOR_OFF 9699344
#define WSUM_OFF   9764880
#define SCORE_OFF  65536

__device__ __forceinline__ unsigned monof(float f) {
  unsigned u = __float_as_uint(f);
  return (u & 0x80000000u) ? ~u : (u | 0x80000000u);  // ascending monotone map
}

__global__ void k_zero(unsigned* __restrict__ cnt, float* __restrict__ wsum,
                       float* __restrict__ z) {
  int n = blockIdx.x * 256 + threadIdx.x;
  if (n < NN) { cnt[n] = 0u; wsum[n] = 1.0f; z[n] = 0.0f; }
}

__global__ void k_hist(const int* __restrict__ ei, const float* __restrict__ w,
                       unsigned* __restrict__ cnt, float* __restrict__ wsum) {
  int e = blockIdx.x * 256 + threadIdx.x;
  if (e < NE) {
    int c = ei[NE + e];
    atomicAdd(&cnt[c], 1u);
    unsafeAtomicAdd(&wsum[c], w[e]);
  }
}

// Per graph: exclusive prefix over 1024 bins -> rstart/cursor; dinv = rsqrt(wsum).
__global__ __launch_bounds__(256) void k_prefix(const unsigned* __restrict__ cnt,
    const float* __restrict__ wsum, unsigned* __restrict__ rstart,
    unsigned* __restrict__ cursor, float* __restrict__ dinv) {
  __shared__ unsigned tmp[2][256];
  int g = blockIdx.x, t = threadIdx.x;
  int base = g << 10;
  unsigned c[4], sum = 0;
#pragma unroll
  for (int u = 0; u < 4; ++u) { c[u] = cnt[base + t * 4 + u]; sum += c[u]; }
  tmp[0][t] = sum;
  __syncthreads();
  int pin = 0;
  for (int off = 1; off < 256; off <<= 1) {
    int pout = pin ^ 1;
    unsigned v = tmp[pin][t];
    if (t >= off) v += tmp[pin][t - off];
    tmp[pout][t] = v;
    __syncthreads();
    pin = pout;
  }
  unsigned run = (t == 0) ? 0u : tmp[pin][t - 1];
#pragma unroll
  for (int u = 0; u < 4; ++u) {
    unsigned pos = (unsigned)(g << 13) + run;   // g*8192 + prefix
    rstart[base + t * 4 + u] = pos;
    cursor[base + t * 4 + u] = pos;
    run += c[u];
  }
#pragma unroll
  for (int u = 0; u < 4; ++u) {
    int n = base + t * 4 + u;
    dinv[n] = rsqrtf(wsum[n]);                   // wsum >= 1 always
  }
  if (g == 0 && t == 0) rstart[NN] = NE;
}

// Scatter edges to dest-sorted CSR: csr[pos] = (coef bits << 32) | local_row
__global__ void k_scatter(const int* __restrict__ ei, const float* __restrict__ w,
                          const float* __restrict__ dinv, unsigned* __restrict__ cursor,
                          unsigned long long* __restrict__ csr) {
  int e = blockIdx.x * 256 + threadIdx.x;
  if (e < NE) {
    int r = ei[e], c = ei[NE + e];
    float cf = w[e] * dinv[r] * dinv[c];
    unsigned pos = atomicAdd(&cursor[c], 1u);
    csr[pos] = ((unsigned long long)__float_as_uint(cf) << 32) | (unsigned)(r & 1023);
  }
}

// Aggregate x over normalized adjacency into ybuf (chunk of 32 graphs).
// Block = (graph g, 8-col chunk). xs staged in LDS; each 8-lane group owns
// 32 dest nodes; per-node in-edge segment summed in a REGISTER (no atomics).
__global__ __launch_bounds__(256, 3) void k_aggx(const float* __restrict__ x,
    const unsigned long long* __restrict__ csr, const unsigned* __restrict__ rstart,
    const float* __restrict__ dinv, float* __restrict__ ybuf, int gbase) {
  __shared__ float xs[1024 * 9];    // 36 KB, stride-9 rows
  __shared__ unsigned rp[1025];
  __shared__ float dv2[1024];
  int bid = blockIdx.x;
  int g  = bid & 31;                // graph g -> XCD g%8 (L2 locality for x-slice)
  int cc = bid >> 5;
  int gg = gbase + g;
  int c0 = cc * 8;
  int t = threadIdx.x;
  int nbase = gg << 10;
  for (int i = t; i < 1024; i += 256) {
    rp[i] = rstart[nbase + i];
    float dv = dinv[nbase + i];
    dv2[i] = dv * dv;
  }
  if (t == 0) rp[1024] = rstart[nbase + 1024];
#pragma unroll
  for (int sg = 0; sg < 4; ++sg) {
    float v[8];
#pragma unroll
    for (int u = 0; u < 8; ++u) {
      int i = t + (sg * 8 + u) * 256;
      v[u] = x[(nbase + (i >> 3)) * 256 + c0 + (i & 7)];
    }
#pragma unroll
    for (int u = 0; u < 8; ++u) {
      int i = t + (sg * 8 + u) * 256;
      xs[(i >> 3) * 9 + (i & 7)] = v[u];
    }
  }
  __syncthreads();
  int j = t & 7, grp = t >> 3;      // 32 groups of 8 lanes
  int d0 = grp * 32;                // 32 dest nodes per group
  for (int dd = 0; dd < 32; ++dd) {
    int d = d0 + dd;
    unsigned s = rp[d], epos = rp[d + 1];
    float a = dv2[d] * xs[d * 9 + j];
    unsigned e = s;
    for (; e + 4 <= epos; e += 4) {
      unsigned long long p0 = csr[e], p1 = csr[e + 1], p2 = csr[e + 2], p3 = csr[e + 3];
      a += __uint_as_float((unsigned)(p0 >> 32)) * xs[(unsigned)(p0 & 1023) * 9 + j];
      a += __uint_as_float((unsigned)(p1 >> 32)) * xs[(unsigned)(p1 & 1023) * 9 + j];
      a += __uint_as_float((unsigned)(p2 >> 32)) * xs[(unsigned)(p2 & 1023) * 9 + j];
      a += __uint_as_float((unsigned)(p3 >> 32)) * xs[(unsigned)(p3 & 1023) * 9 + j];
    }
    for (; e < epos; ++e) {
      unsigned long long p = csr[e];
      a += __uint_as_float((unsigned)(p >> 32)) * xs[(unsigned)(p & 1023) * 9 + j];
    }
    ybuf[((g << 10) + d) * 256 + c0 + j] = a;
  }
}

// fp32 GEMM y(32768x256) @ W1(256x512), fused +b1 -> LeakyReLU -> dot W2 -> atomic z
__global__ __launch_bounds__(256) void k_gemm(const float* __restrict__ ybuf,
    const float* __restrict__ W1, const float* __restrict__ b1,
    const float* __restrict__ W2, float* __restrict__ z, int node_base) {
  __shared__ float As[32][68];
  __shared__ float Bs[32][132];
  int bx = blockIdx.x & 3;
  int by = blockIdx.x >> 2;
  int t = threadIdx.x;
  int tx = t & 15, ty = t >> 4;
  int row0 = by * 64;
  float acc[4][8] = {};
  for (int kt = 0; kt < 256; kt += 32) {
    __syncthreads();
#pragma unroll
    for (int s = 0; s < 8; ++s) {
      int i = t + s * 256;
      As[i & 31][i >> 5] = ybuf[(row0 + (i >> 5)) * 256 + kt + (i & 31)];
    }
#pragma unroll
    for (int s = 0; s < 16; ++s) {
      int i = t + s * 256;
      Bs[i >> 7][i & 127] = W1[(kt + (i >> 7)) * 512 + bx * 128 + (i & 127)];
    }
    __syncthreads();
#pragma unroll
    for (int kk = 0; kk < 32; ++kk) {
      float4 a4  = *(const float4*)&As[kk][ty * 4];
      float4 b4a = *(const float4*)&Bs[kk][tx * 4];
      float4 b4b = *(const float4*)&Bs[kk][tx * 4 + 64];
      float a[4]  = {a4.x, a4.y, a4.z, a4.w};
      float bb[8] = {b4a.x, b4a.y, b4a.z, b4a.w, b4b.x, b4b.y, b4b.z, b4b.w};
#pragma unroll
      for (int r = 0; r < 4; ++r)
#pragma unroll
        for (int c = 0; c < 8; ++c)
          acc[r][c] += a[r] * bb[c];
    }
  }
  int ca = bx * 128 + tx * 4, cb = ca + 64;
  float b1v[8], w2v[8];
#pragma unroll
  for (int c = 0; c < 8; ++c) {
    int col = (c < 4) ? ca + c : cb + (c - 4);
    b1v[c] = b1[col]; w2v[c] = W2[col];
  }
  float p[4] = {};
#pragma unroll
  for (int r = 0; r < 4; ++r)
#pragma unroll
    for (int c = 0; c < 8; ++c) {
      float v = acc[r][c] + b1v[c];
      v = v > 0.0f ? v : 0.01f * v;
      p[r] += v * w2v[c];
    }
#pragma unroll
  for (int o = 8; o > 0; o >>= 1)
#pragma unroll
    for (int r = 0; r < 4; ++r)
      p[r] += __shfl_xor(p[r], o, 16);
  if (tx == 0) {
    int node = node_base + row0 + ty * 4;
#pragma unroll
    for (int r = 0; r < 4; ++r)
      unsafeAtomicAdd(&z[node + r], p[r]);
  }
}

__global__ void k_mask_init(int* __restrict__ mask) {
  int n = blockIdx.x * 256 + threadIdx.x;
  if (n < NN) mask[n] = -1;
}

// score[n] = b2 + dinv[n]^2*z[n] + sum_{e in seg(n)} coef[e]*z[global_row]
__global__ void k_score(const unsigned long long* __restrict__ csr,
                        const unsigned* __restrict__ rstart,
                        const float* __restrict__ dinv, const float* __restrict__ z,
                        const float* __restrict__ b2, float* __restrict__ score) {
  int n = blockIdx.x * 256 + threadIdx.x;
  if (n >= NN) return;
  int nb = n & ~1023;
  float dv = dinv[n];
  float a = b2[0] + dv * dv * z[n];
  unsigned s = rstart[n], epos = rstart[n + 1];
  for (unsigned e = s; e < epos; ++e) {
    unsigned long long p = csr[e];
    a += __uint_as_float((unsigned)(p >> 32)) * z[nb + (unsigned)(p & 1023)];
  }
  score[n] = a;
}

__device__ void bitonic(unsigned long long* keys, int n, int t, int nt) {
  for (int k = 2; k <= n; k <<= 1)
    for (int jj = k >> 1; jj > 0; jj >>= 1) {
      __syncthreads();
      for (int i = t; i < n; i += nt) {
        int ixj = i ^ jj;
        if (ixj > i) {
          unsigned long long a = keys[i], c = keys[ixj];
          bool up = ((i & k) == 0);
          if ((a > c) == up) { keys[i] = c; keys[ixj] = a; }
        }
      }
    }
  __syncthreads();
}

__global__ __launch_bounds__(256) void k_topk(const float* __restrict__ score,
                                              int* __restrict__ mask,
                                              float* __restrict__ out) {
  __shared__ unsigned long long keys[1024];
  int b = blockIdx.x, t = threadIdx.x;
  int base = b << 10;
  if (t < 64) {
    float v = score[base + t];
    keys[t] = ((unsigned long long)(~monof(v)) << 32) | (unsigned)t;
    out[O6 + b * 64 + t] = v;
    out[O7 + b * 64 + t] = (float)b;
  }
  __syncthreads();
  bitonic(keys, 64, t, 256);
  if (t < 3) {
    int idx = (int)(keys[t] & 0xFFFFFFFFull);
    int node = base + idx;
    int pos = b * 3 + t;
    mask[node] = pos;
    out[O4 + pos] = (float)node;
    out[O5 + pos] = score[node];
    out[O3 + pos] = (float)b;
  }
  __syncthreads();
  for (int i = t; i < 1024; i += 256) {
    if (i < 960) {
      float v = score[base + 64 + i];
      keys[i] = ((unsigned long long)(~monof(v)) << 32) | (unsigned)i;
    } else {
      keys[i] = 0xFFFFFFFFFFFFFFFFull;
    }
  }
  __syncthreads();
  bitonic(keys, 1024, t, 256);
  for (int r = t; r < 480; r += 256) {
    int idx = (int)(keys[r] & 0xFFFFFFFFull);
    int node = base + 64 + idx;
    int pos = 192 + b * 480 + r;
    mask[node] = pos;
    out[O4 + pos] = (float)node;
    out[O5 + pos] = score[node];
    out[O3 + pos] = (float)b;
  }
}

__global__ void k_edges(const int* __restrict__ ei, const float* __restrict__ w,
                        const int* __restrict__ mask, float* __restrict__ out) {
  int e = blockIdx.x * 256 + threadIdx.x;
  if (e >= NE) return;
  int nr = mask[ei[e]];
  int nc = mask[ei[NE + e]];
  bool keep = (nr >= 0) && (nc >= 0);
  out[O1 + e]      = keep ? (float)nr : -1.0f;
  out[O1 + NE + e] = keep ? (float)nc : -1.0f;
  out[O2 + e]      = keep ? w[e] : 0.0f;
  out[O8 + e]      = keep ? 1.0f : 0.0f;
}

__global__ void k_xout(const float* __restrict__ x, const float* __restrict__ permF,
                       const float* __restrict__ scoreP, float* __restrict__ out) {
  int i = blockIdx.x;
  int node = (int)permF[i];
  float s = scoreP[i];
  const float4* xr = (const float4*)&x[node * 256];
  float4* o = (float4*)&out[i * 256];
  float4 v = xr[threadIdx.x];
  o[threadIdx.x] = make_float4(v.x * s, v.y * s, v.z * s, v.w * s);
}

extern "C" void kernel_launch(void* const* d_in, const int* in_sizes, int n_in,
                              void* d_out, int out_size, void* d_ws, size_t ws_size,
                              hipStream_t stream) {
  (void)in_sizes; (void)n_in; (void)out_size; (void)d_ws; (void)ws_size;
  const float* x  = (const float*)d_in[0];
  const int*   ei = (const int*)d_in[1];
  const float* w  = (const float*)d_in[2];
  const float* W1 = (const float*)d_in[4];
  const float* b1 = (const float*)d_in[5];
  const float* W2 = (const float*)d_in[6];
  const float* b2 = (const float*)d_in[7];
  float* out    = (float*)d_out;
  float* ybuf   = out;
  unsigned long long* csr = (unsigned long long*)(out + CSR_OFF);
  float* dinv   = out + DINV_OFF;
  float* z      = out + Z_OFF;
  unsigned* cnt    = (unsigned*)(out + CNT_OFF);
  unsigned* rstart = (unsigned*)(out + RSTART_OFF);
  unsigned* cursor = (unsigned*)(out + CURSOR_OFF);
  float* wsum   = out + WSUM_OFF;
  float* score  = out + SCORE_OFF;
  int*   mask   = (int*)d_out;

  k_zero<<<256, 256, 0, stream>>>(cnt, wsum, z);
  k_hist<<<2048, 256, 0, stream>>>(ei, w, cnt, wsum);
  k_prefix<<<64, 256, 0, stream>>>(cnt, wsum, rstart, cursor, dinv);
  k_scatter<<<2048, 256, 0, stream>>>(ei, w, dinv, cursor, csr);
  for (int ch = 0; ch < 2; ++ch) {
    k_aggx<<<1024, 256, 0, stream>>>(x, csr, rstart, dinv, ybuf, ch * 32);
    k_gemm<<<2048, 256, 0, stream>>>(ybuf, W1, b1, W2, z, ch * 32768);
  }
  k_mask_init<<<256, 256, 0, stream>>>(mask);
  k_score<<<256, 256, 0, stream>>>(csr, rstart, dinv, z, b2, score);
  k_topk<<<64, 256, 0, stream>>>(score, mask, out);
  k_edges<<<2048, 256, 0, stream>>>(ei, w, mask, out);
  k_xout<<<30912, 64, 0, stream>>>(x, out + O4, out + O5, out);
}

// Round 5
// 394.347 us; speedup vs baseline: 2.5583x; 1.3675x over previous
//
#include <hip/hip_runtime.h>

// Problem constants
#define NN   65536      // N nodes
#define NE   524288     // E edges
#define EPG  8192       // edges per graph

// Output float offsets in d_out (total 10111552 floats)
#define O1 7913472      // ei_new (2*E)
#define O2 8962048      // ea_new (E)
#define O3 9486336      // batch_out (30912)
#define O4 9517248      // perm (30912)
#define O5 9548160      // score_perm (30912)
#define O6 9579072      // sentence_scores (4096)
#define O7 9583168      // sentence_batch (4096)
#define O8 9587264      // keep (E)

// Scratch placement (float offsets), lifetime-verified:
//  yhi/ylo [0, 8388608)        bf16 planes of y (per 32-graph chunk); die after last k_gemm
//  csr    [8388608, 9437184)   u64[524288]; dies after k_score (before k_edges O1/O2)
//  dinv   [9437184, 9502720)   dies after k_score (k_topk writes O3.. later)
//  z      [9502720, 9568256)   dies after k_score (k_topk writes O4/O5 later)
//  cnt    [9568256, 9633792)   dies after k_prefix -> REUSED as w1hi (dies before k_edges O8)
//  rstart [9633792, 9699329)   u32[65537]; dies after k_score
//  cursor [9699344, 9764880)   dies after k_scatter
//  wsum   [9764880, 9830416)   dies after k_prefix -> REUSED as w1lo (dies before k_edges O8)
//  score  [65536, 131072)      written after y planes die... (see note: score written after GEMMs)
//  mask   ints [0, 65536)      written after GEMMs; read k_edges; k_xout overwrites last
#define CSR_OFF    8388608
#define DINV_OFF   9437184
#define Z_OFF      9502720
#define CNT_OFF    9568256
#define RSTART_OFF 9633792
#define CURSOR_OFF 9699344
#define WSUM_OFF   9764880
#define SCORE_OFF  65536
#define YLO_OFF    4194304   // ushort-plane offsets: yhi at float 0, ylo at float 4194304

typedef __attribute__((ext_vector_type(8))) short bfrag;
typedef __attribute__((ext_vector_type(4))) float f32x4;
typedef __attribute__((ext_vector_type(8))) unsigned short us8;

__device__ __forceinline__ unsigned monof(float f) {
  unsigned u = __float_as_uint(f);
  return (u & 0x80000000u) ? ~u : (u | 0x80000000u);  // ascending monotone map
}

__device__ __forceinline__ unsigned short bf16rne(float f) {
  unsigned u = __float_as_uint(f);
  return (unsigned short)((u + 0x7FFFu + ((u >> 16) & 1u)) >> 16);
}

__global__ void k_zero(unsigned* __restrict__ cnt, float* __restrict__ wsum,
                       float* __restrict__ z) {
  int n = blockIdx.x * 256 + threadIdx.x;
  if (n < NN) { cnt[n] = 0u; wsum[n] = 1.0f; z[n] = 0.0f; }
}

__global__ void k_hist(const int* __restrict__ ei, const float* __restrict__ w,
                       unsigned* __restrict__ cnt, float* __restrict__ wsum) {
  int e = blockIdx.x * 256 + threadIdx.x;
  if (e < NE) {
    int c = ei[NE + e];
    atomicAdd(&cnt[c], 1u);
    unsafeAtomicAdd(&wsum[c], w[e]);
  }
}

// Per graph: exclusive prefix over 1024 bins -> rstart/cursor; dinv = rsqrt(wsum).
__global__ __launch_bounds__(256) void k_prefix(const unsigned* __restrict__ cnt,
    const float* __restrict__ wsum, unsigned* __restrict__ rstart,
    unsigned* __restrict__ cursor, float* __restrict__ dinv) {
  __shared__ unsigned tmp[2][256];
  int g = blockIdx.x, t = threadIdx.x;
  int base = g << 10;
  unsigned c[4], sum = 0;
#pragma unroll
  for (int u = 0; u < 4; ++u) { c[u] = cnt[base + t * 4 + u]; sum += c[u]; }
  tmp[0][t] = sum;
  __syncthreads();
  int pin = 0;
  for (int off = 1; off < 256; off <<= 1) {
    int pout = pin ^ 1;
    unsigned v = tmp[pin][t];
    if (t >= off) v += tmp[pin][t - off];
    tmp[pout][t] = v;
    __syncthreads();
    pin = pout;
  }
  unsigned run = (t == 0) ? 0u : tmp[pin][t - 1];
#pragma unroll
  for (int u = 0; u < 4; ++u) {
    unsigned pos = (unsigned)(g << 13) + run;   // g*8192 + prefix
    rstart[base + t * 4 + u] = pos;
    cursor[base + t * 4 + u] = pos;
    run += c[u];
  }
#pragma unroll
  for (int u = 0; u < 4; ++u) {
    int n = base + t * 4 + u;
    dinv[n] = rsqrtf(wsum[n]);                   // wsum >= 1 always
  }
  if (g == 0 && t == 0) rstart[NN] = NE;
}

// Split+transpose W1 [256k][512c] fp32 -> w1hi/w1lo [512c][256k] bf16 (k-contiguous)
__global__ __launch_bounds__(256) void k_w1t(const float* __restrict__ W1,
    unsigned short* __restrict__ hi, unsigned short* __restrict__ lo) {
  __shared__ unsigned short sh[64][72], sl[64][72];
  int bk = blockIdx.x & 3, bc = blockIdx.x >> 2;
  int k0 = bk * 64, c0 = bc * 64;
  int t = threadIdx.x;
#pragma unroll
  for (int s = 0; s < 16; ++s) {
    int i = t + s * 256;
    int k = i >> 6, c = i & 63;
    float v = W1[(k0 + k) * 512 + c0 + c];
    unsigned short h = bf16rne(v);
    float hf = __uint_as_float((unsigned)h << 16);
    sh[c][k] = h;
    sl[c][k] = bf16rne(v - hf);
  }
  __syncthreads();
#pragma unroll
  for (int s = 0; s < 16; ++s) {
    int i = t + s * 256;
    int c = i >> 6, k = i & 63;
    hi[(c0 + c) * 256 + k0 + k] = sh[c][k];
    lo[(c0 + c) * 256 + k0 + k] = sl[c][k];
  }
}

// Scatter edges to dest-sorted CSR: csr[pos] = (coef bits << 32) | local_row
__global__ void k_scatter(const int* __restrict__ ei, const float* __restrict__ w,
                          const float* __restrict__ dinv, unsigned* __restrict__ cursor,
                          unsigned long long* __restrict__ csr) {
  int e = blockIdx.x * 256 + threadIdx.x;
  if (e < NE) {
    int r = ei[e], c = ei[NE + e];
    float cf = w[e] * dinv[r] * dinv[c];
    unsigned pos = atomicAdd(&cursor[c], 1u);
    csr[pos] = ((unsigned long long)__float_as_uint(cf) << 32) | (unsigned)(r & 1023);
  }
}

// Aggregate x over normalized adjacency -> y, written as bf16 hi/lo planes.
// Block = (graph g, 8-col chunk). xs staged in LDS; each 8-lane group owns
// 32 dest nodes; per-node in-edge segment summed in a REGISTER (no atomics).
__global__ __launch_bounds__(256, 3) void k_aggx(const float* __restrict__ x,
    const unsigned long long* __restrict__ csr, const unsigned* __restrict__ rstart,
    const float* __restrict__ dinv, unsigned short* __restrict__ yhi,
    unsigned short* __restrict__ ylo, int gbase) {
  __shared__ float xs[1024 * 9];    // 36 KB, stride-9 rows
  __shared__ unsigned rp[1025];
  __shared__ float dv2[1024];
  int bid = blockIdx.x;
  int g  = bid & 31;                // graph g -> XCD g%8 (L2 locality for x-slice)
  int cc = bid >> 5;
  int gg = gbase + g;
  int c0 = cc * 8;
  int t = threadIdx.x;
  int nbase = gg << 10;
  for (int i = t; i < 1024; i += 256) {
    rp[i] = rstart[nbase + i];
    float dv = dinv[nbase + i];
    dv2[i] = dv * dv;
  }
  if (t == 0) rp[1024] = rstart[nbase + 1024];
#pragma unroll
  for (int sg = 0; sg < 4; ++sg) {
    float v[8];
#pragma unroll
    for (int u = 0; u < 8; ++u) {
      int i = t + (sg * 8 + u) * 256;
      v[u] = x[(nbase + (i >> 3)) * 256 + c0 + (i & 7)];
    }
#pragma unroll
    for (int u = 0; u < 8; ++u) {
      int i = t + (sg * 8 + u) * 256;
      xs[(i >> 3) * 9 + (i & 7)] = v[u];
    }
  }
  __syncthreads();
  int j = t & 7, grp = t >> 3;      // 32 groups of 8 lanes
  int d0 = grp * 32;                // 32 dest nodes per group
  for (int dd = 0; dd < 32; ++dd) {
    int d = d0 + dd;
    unsigned s = rp[d], epos = rp[d + 1];
    float a = dv2[d] * xs[d * 9 + j];
    unsigned e = s;
    for (; e + 4 <= epos; e += 4) {
      unsigned long long p0 = csr[e], p1 = csr[e + 1], p2 = csr[e + 2], p3 = csr[e + 3];
      a += __uint_as_float((unsigned)(p0 >> 32)) * xs[(unsigned)(p0 & 1023) * 9 + j];
      a += __uint_as_float((unsigned)(p1 >> 32)) * xs[(unsigned)(p1 & 1023) * 9 + j];
      a += __uint_as_float((unsigned)(p2 >> 32)) * xs[(unsigned)(p2 & 1023) * 9 + j];
      a += __uint_as_float((unsigned)(p3 >> 32)) * xs[(unsigned)(p3 & 1023) * 9 + j];
    }
    for (; e < epos; ++e) {
      unsigned long long p = csr[e];
      a += __uint_as_float((unsigned)(p >> 32)) * xs[(unsigned)(p & 1023) * 9 + j];
    }
    int idx = ((g << 10) + d) * 256 + c0 + j;
    unsigned short h = bf16rne(a);
    yhi[idx] = h;
    ylo[idx] = bf16rne(a - __uint_as_float((unsigned)h << 16));
  }
}

// MFMA GEMM: h = y(32768x256) @ W1(256x512) via bf16 hi/lo 3-product split,
// fused +b1 -> LeakyReLU -> dot W2 -> atomic z.  128x128 tile, 4 waves (64x64).
__global__ __launch_bounds__(256, 2) void k_gemm(
    const unsigned short* __restrict__ yhi, const unsigned short* __restrict__ ylo,
    const unsigned short* __restrict__ w1hi, const unsigned short* __restrict__ w1lo,
    const float* __restrict__ b1, const float* __restrict__ W2,
    float* __restrict__ z, int node_base) {
  __shared__ unsigned short Ah_s[128 * 40], Al_s[128 * 40];  // [row][40] ushort, 80B stride
  __shared__ unsigned short Bh_s[128 * 40], Bl_s[128 * 40];  // [col][40]
  int bx = blockIdx.x & 3, by = blockIdx.x >> 2;
  int r0 = by * 128, c0 = bx * 128;
  int t = threadIdx.x;
  int lane = t & 63, wid = t >> 6;
  int wr = wid >> 1, wc = wid & 1;         // wave tile origin (wr*64, wc*64)
  int lr = lane & 15, hg = lane >> 4;
  f32x4 acc[4][4];
#pragma unroll
  for (int m = 0; m < 4; ++m)
#pragma unroll
    for (int n = 0; n < 4; ++n)
      acc[m][n] = (f32x4){0.0f, 0.0f, 0.0f, 0.0f};
  int rr = t >> 2, kq = (t & 3) * 8;       // staging: rows rr, rr+64; 8-elem k-chunk
  for (int kt = 0; kt < 256; kt += 32) {
    us8 va0 = *(const us8*)&yhi[(r0 + rr) * 256 + kt + kq];
    us8 va1 = *(const us8*)&yhi[(r0 + rr + 64) * 256 + kt + kq];
    us8 vb0 = *(const us8*)&ylo[(r0 + rr) * 256 + kt + kq];
    us8 vb1 = *(const us8*)&ylo[(r0 + rr + 64) * 256 + kt + kq];
    us8 vc0 = *(const us8*)&w1hi[(c0 + rr) * 256 + kt + kq];
    us8 vc1 = *(const us8*)&w1hi[(c0 + rr + 64) * 256 + kt + kq];
    us8 vd0 = *(const us8*)&w1lo[(c0 + rr) * 256 + kt + kq];
    us8 vd1 = *(const us8*)&w1lo[(c0 + rr + 64) * 256 + kt + kq];
    __syncthreads();                        // prev-step frag reads complete
    *(us8*)&Ah_s[rr * 40 + kq] = va0;  *(us8*)&Ah_s[(rr + 64) * 40 + kq] = va1;
    *(us8*)&Al_s[rr * 40 + kq] = vb0;  *(us8*)&Al_s[(rr + 64) * 40 + kq] = vb1;
    *(us8*)&Bh_s[rr * 40 + kq] = vc0;  *(us8*)&Bh_s[(rr + 64) * 40 + kq] = vc1;
    *(us8*)&Bl_s[rr * 40 + kq] = vd0;  *(us8*)&Bl_s[(rr + 64) * 40 + kq] = vd1;
    __syncthreads();
    bfrag Ah[4], Al[4], Bh[4], Bl[4];
#pragma unroll
    for (int m = 0; m < 4; ++m) {
      int ra = (wr * 64 + m * 16 + lr) * 40 + hg * 8;
      Ah[m] = *(const bfrag*)&Ah_s[ra];
      Al[m] = *(const bfrag*)&Al_s[ra];
      int rb = (wc * 64 + m * 16 + lr) * 40 + hg * 8;
      Bh[m] = *(const bfrag*)&Bh_s[rb];
      Bl[m] = *(const bfrag*)&Bl_s[rb];
    }
#pragma unroll
    for (int m = 0; m < 4; ++m)
#pragma unroll
      for (int n = 0; n < 4; ++n) {
        acc[m][n] = __builtin_amdgcn_mfma_f32_16x16x32_bf16(Ah[m], Bh[n], acc[m][n], 0, 0, 0);
        acc[m][n] = __builtin_amdgcn_mfma_f32_16x16x32_bf16(Ah[m], Bl[n], acc[m][n], 0, 0, 0);
        acc[m][n] = __builtin_amdgcn_mfma_f32_16x16x32_bf16(Al[m], Bh[n], acc[m][n], 0, 0, 0);
      }
  }
  // epilogue: +b1, LeakyReLU, dot W2, reduce over the 16 col-lanes, atomic z
  float p[4][4];
#pragma unroll
  for (int m = 0; m < 4; ++m)
#pragma unroll
    for (int i = 0; i < 4; ++i) p[m][i] = 0.0f;
#pragma unroll
  for (int n = 0; n < 4; ++n) {
    int col = c0 + wc * 64 + n * 16 + lr;
    float b1v = b1[col], w2v = W2[col];
#pragma unroll
    for (int m = 0; m < 4; ++m)
#pragma unroll
      for (int i = 0; i < 4; ++i) {
        float v = acc[m][n][i] + b1v;
        v = v > 0.0f ? v : 0.01f * v;
        p[m][i] += v * w2v;
      }
  }
#pragma unroll
  for (int off = 8; off > 0; off >>= 1)
#pragma unroll
    for (int m = 0; m < 4; ++m)
#pragma unroll
      for (int i = 0; i < 4; ++i)
        p[m][i] += __shfl_xor(p[m][i], off, 16);
  if (lr == 0) {
    int rbase = node_base + r0 + wr * 64 + hg * 4;
#pragma unroll
    for (int m = 0; m < 4; ++m)
#pragma unroll
      for (int i = 0; i < 4; ++i)
        unsafeAtomicAdd(&z[rbase + m * 16 + i], p[m][i]);
  }
}

__global__ void k_mask_init(int* __restrict__ mask) {
  int n = blockIdx.x * 256 + threadIdx.x;
  if (n < NN) mask[n] = -1;
}

// score[n] = b2 + dinv[n]^2*z[n] + sum_{e in seg(n)} coef[e]*z[global_row]
__global__ void k_score(const unsigned long long* __restrict__ csr,
                        const unsigned* __restrict__ rstart,
                        const float* __restrict__ dinv, const float* __restrict__ z,
                        const float* __restrict__ b2, float* __restrict__ score) {
  int n = blockIdx.x * 256 + threadIdx.x;
  if (n >= NN) return;
  int nb = n & ~1023;
  float dv = dinv[n];
  float a = b2[0] + dv * dv * z[n];
  unsigned s = rstart[n], epos = rstart[n + 1];
  for (unsigned e = s; e < epos; ++e) {
    unsigned long long p = csr[e];
    a += __uint_as_float((unsigned)(p >> 32)) * z[nb + (unsigned)(p & 1023)];
  }
  score[n] = a;
}

__device__ void bitonic(unsigned long long* keys, int n, int t, int nt) {
  for (int k = 2; k <= n; k <<= 1)
    for (int jj = k >> 1; jj > 0; jj >>= 1) {
      __syncthreads();
      for (int i = t; i < n; i += nt) {
        int ixj = i ^ jj;
        if (ixj > i) {
          unsigned long long a = keys[i], c = keys[ixj];
          bool up = ((i & k) == 0);
          if ((a > c) == up) { keys[i] = c; keys[ixj] = a; }
        }
      }
    }
  __syncthreads();
}

__global__ __launch_bounds__(256) void k_topk(const float* __restrict__ score,
                                              int* __restrict__ mask,
                                              float* __restrict__ out) {
  __shared__ unsigned long long keys[1024];
  int b = blockIdx.x, t = threadIdx.x;
  int base = b << 10;
  if (t < 64) {
    float v = score[base + t];
    keys[t] = ((unsigned long long)(~monof(v)) << 32) | (unsigned)t;
    out[O6 + b * 64 + t] = v;
    out[O7 + b * 64 + t] = (float)b;
  }
  __syncthreads();
  bitonic(keys, 64, t, 256);
  if (t < 3) {
    int idx = (int)(keys[t] & 0xFFFFFFFFull);
    int node = base + idx;
    int pos = b * 3 + t;
    mask[node] = pos;
    out[O4 + pos] = (float)node;
    out[O5 + pos] = score[node];
    out[O3 + pos] = (float)b;
  }
  __syncthreads();
  for (int i = t; i < 1024; i += 256) {
    if (i < 960) {
      float v = score[base + 64 + i];
      keys[i] = ((unsigned long long)(~monof(v)) << 32) | (unsigned)i;
    } else {
      keys[i] = 0xFFFFFFFFFFFFFFFFull;
    }
  }
  __syncthreads();
  bitonic(keys, 1024, t, 256);
  for (int r = t; r < 480; r += 256) {
    int idx = (int)(keys[r] & 0xFFFFFFFFull);
    int node = base + 64 + idx;
    int pos = 192 + b * 480 + r;
    mask[node] = pos;
    out[O4 + pos] = (float)node;
    out[O5 + pos] = score[node];
    out[O3 + pos] = (float)b;
  }
}

__global__ void k_edges(const int* __restrict__ ei, const float* __restrict__ w,
                        const int* __restrict__ mask, float* __restrict__ out) {
  int e = blockIdx.x * 256 + threadIdx.x;
  if (e >= NE) return;
  int nr = mask[ei[e]];
  int nc = mask[ei[NE + e]];
  bool keep = (nr >= 0) && (nc >= 0);
  out[O1 + e]      = keep ? (float)nr : -1.0f;
  out[O1 + NE + e] = keep ? (float)nc : -1.0f;
  out[O2 + e]      = keep ? w[e] : 0.0f;
  out[O8 + e]      = keep ? 1.0f : 0.0f;
}

__global__ void k_xout(const float* __restrict__ x, const float* __restrict__ permF,
                       const float* __restrict__ scoreP, float* __restrict__ out) {
  int i = blockIdx.x;
  int node = (int)permF[i];
  float s = scoreP[i];
  const float4* xr = (const float4*)&x[node * 256];
  float4* o = (float4*)&out[i * 256];
  float4 v = xr[threadIdx.x];
  o[threadIdx.x] = make_float4(v.x * s, v.y * s, v.z * s, v.w * s);
}

extern "C" void kernel_launch(void* const* d_in, const int* in_sizes, int n_in,
                              void* d_out, int out_size, void* d_ws, size_t ws_size,
                              hipStream_t stream) {
  (void)in_sizes; (void)n_in; (void)out_size; (void)d_ws; (void)ws_size;
  const float* x  = (const float*)d_in[0];
  const int*   ei = (const int*)d_in[1];
  const float* w  = (const float*)d_in[2];
  const float* W1 = (const float*)d_in[4];
  const float* b1 = (const float*)d_in[5];
  const float* W2 = (const float*)d_in[6];
  const float* b2 = (const float*)d_in[7];
  float* out    = (float*)d_out;
  unsigned short* yhi = (unsigned short*)out;                  // [32768*256] per chunk
  unsigned short* ylo = (unsigned short*)(out + YLO_OFF);
  unsigned long long* csr = (unsigned long long*)(out + CSR_OFF);
  float* dinv   = out + DINV_OFF;
  float* z      = out + Z_OFF;
  unsigned* cnt    = (unsigned*)(out + CNT_OFF);
  unsigned* rstart = (unsigned*)(out + RSTART_OFF);
  unsigned* cursor = (unsigned*)(out + CURSOR_OFF);
  float* wsum   = out + WSUM_OFF;
  unsigned short* w1hi = (unsigned short*)(out + CNT_OFF);     // reuse cnt after k_prefix
  unsigned short* w1lo = (unsigned short*)(out + WSUM_OFF);    // reuse wsum after k_prefix
  float* score  = out + SCORE_OFF;
  int*   mask   = (int*)d_out;

  k_zero<<<256, 256, 0, stream>>>(cnt, wsum, z);
  k_hist<<<2048, 256, 0, stream>>>(ei, w, cnt, wsum);
  k_prefix<<<64, 256, 0, stream>>>(cnt, wsum, rstart, cursor, dinv);
  k_w1t<<<32, 256, 0, stream>>>(W1, w1hi, w1lo);               // cnt/wsum dead now
  k_scatter<<<2048, 256, 0, stream>>>(ei, w, dinv, cursor, csr);
  for (int ch = 0; ch < 2; ++ch) {
    k_aggx<<<1024, 256, 0, stream>>>(x, csr, rstart, dinv, yhi, ylo, ch * 32);
    k_gemm<<<1024, 256, 0, stream>>>(yhi, ylo, w1hi, w1lo, b1, W2, z, ch * 32768);
  }
  k_mask_init<<<256, 256, 0, stream>>>(mask);
  k_score<<<256, 256, 0, stream>>>(csr, rstart, dinv, z, b2, score);
  k_topk<<<64, 256, 0, stream>>>(score, mask, out);
  k_edges<<<2048, 256, 0, stream>>>(ei, w, mask, out);
  k_xout<<<30912, 64, 0, stream>>>(x, out + O4, out + O5, out);
}

// Round 6
// 322.732 us; speedup vs baseline: 3.1259x; 1.2219x over previous
//
#include <hip/hip_runtime.h>

// Problem constants
#define NN   65536      // N nodes
#define NE   524288     // E edges
#define EPG  8192       // edges per graph

// Output float offsets in d_out (total 10111552 floats)
#define O1 7913472      // ei_new (2*E)
#define O2 8962048      // ea_new (E)
#define O3 9486336      // batch_out (30912)
#define O4 9517248      // perm (30912)
#define O5 9548160      // score_perm (30912)
#define O6 9579072      // sentence_scores (4096)
#define O7 9583168      // sentence_batch (4096)
#define O8 9587264      // keep (E)

// Scratch placement (float offsets), lifetime-verified (same as R5):
#define CSR_OFF    8388608
#define DINV_OFF   9437184
#define Z_OFF      9502720
#define CNT_OFF    9568256
#define RSTART_OFF 9633792
#define CURSOR_OFF 9699344
#define WSUM_OFF   9764880
#define SCORE_OFF  65536
#define YLO_OFF    4194304   // ushort-plane offsets: yhi at float 0, ylo at float 4194304

typedef __attribute__((ext_vector_type(8))) short bfrag;
typedef __attribute__((ext_vector_type(4))) float f32x4;
typedef __attribute__((ext_vector_type(8))) unsigned short us8;

__device__ __forceinline__ unsigned monof(float f) {
  unsigned u = __float_as_uint(f);
  return (u & 0x80000000u) ? ~u : (u | 0x80000000u);  // ascending monotone map
}

__device__ __forceinline__ unsigned short bf16rne(float f) {
  unsigned u = __float_as_uint(f);
  return (unsigned short)((u + 0x7FFFu + ((u >> 16) & 1u)) >> 16);
}

__global__ void k_zero(unsigned* __restrict__ cnt, float* __restrict__ wsum,
                       float* __restrict__ z) {
  int n = blockIdx.x * 256 + threadIdx.x;
  if (n < NN) { cnt[n] = 0u; wsum[n] = 1.0f; z[n] = 0.0f; }
}

__global__ void k_hist(const int* __restrict__ ei, const float* __restrict__ w,
                       unsigned* __restrict__ cnt, float* __restrict__ wsum) {
  int e = blockIdx.x * 256 + threadIdx.x;
  if (e < NE) {
    int c = ei[NE + e];
    atomicAdd(&cnt[c], 1u);
    unsafeAtomicAdd(&wsum[c], w[e]);
  }
}

// Per graph: exclusive prefix over 1024 bins -> rstart/cursor; dinv = rsqrt(wsum).
__global__ __launch_bounds__(256) void k_prefix(const unsigned* __restrict__ cnt,
    const float* __restrict__ wsum, unsigned* __restrict__ rstart,
    unsigned* __restrict__ cursor, float* __restrict__ dinv) {
  __shared__ unsigned tmp[2][256];
  int g = blockIdx.x, t = threadIdx.x;
  int base = g << 10;
  unsigned c[4], sum = 0;
#pragma unroll
  for (int u = 0; u < 4; ++u) { c[u] = cnt[base + t * 4 + u]; sum += c[u]; }
  tmp[0][t] = sum;
  __syncthreads();
  int pin = 0;
  for (int off = 1; off < 256; off <<= 1) {
    int pout = pin ^ 1;
    unsigned v = tmp[pin][t];
    if (t >= off) v += tmp[pin][t - off];
    tmp[pout][t] = v;
    __syncthreads();
    pin = pout;
  }
  unsigned run = (t == 0) ? 0u : tmp[pin][t - 1];
#pragma unroll
  for (int u = 0; u < 4; ++u) {
    unsigned pos = (unsigned)(g << 13) + run;   // g*8192 + prefix
    rstart[base + t * 4 + u] = pos;
    cursor[base + t * 4 + u] = pos;
    run += c[u];
  }
#pragma unroll
  for (int u = 0; u < 4; ++u) {
    int n = base + t * 4 + u;
    dinv[n] = rsqrtf(wsum[n]);                   // wsum >= 1 always
  }
  if (g == 0 && t == 0) rstart[NN] = NE;
}

// Split+transpose W1 [256k][512c] fp32 -> w1hi/w1lo [512c][256k] bf16 (k-contiguous)
__global__ __launch_bounds__(256) void k_w1t(const float* __restrict__ W1,
    unsigned short* __restrict__ hi, unsigned short* __restrict__ lo) {
  __shared__ unsigned short sh[64][72], sl[64][72];
  int bk = blockIdx.x & 3, bc = blockIdx.x >> 2;
  int k0 = bk * 64, c0 = bc * 64;
  int t = threadIdx.x;
#pragma unroll
  for (int s = 0; s < 16; ++s) {
    int i = t + s * 256;
    int k = i >> 6, c = i & 63;
    float v = W1[(k0 + k) * 512 + c0 + c];
    unsigned short h = bf16rne(v);
    float hf = __uint_as_float((unsigned)h << 16);
    sh[c][k] = h;
    sl[c][k] = bf16rne(v - hf);
  }
  __syncthreads();
#pragma unroll
  for (int s = 0; s < 16; ++s) {
    int i = t + s * 256;
    int c = i >> 6, k = i & 63;
    hi[(c0 + c) * 256 + k0 + k] = sh[c][k];
    lo[(c0 + c) * 256 + k0 + k] = sl[c][k];
  }
}

// Scatter edges to dest-sorted CSR: csr[pos] = (coef bits << 32) | local_row
__global__ void k_scatter(const int* __restrict__ ei, const float* __restrict__ w,
                          const float* __restrict__ dinv, unsigned* __restrict__ cursor,
                          unsigned long long* __restrict__ csr) {
  int e = blockIdx.x * 256 + threadIdx.x;
  if (e < NE) {
    int r = ei[e], c = ei[NE + e];
    float cf = w[e] * dinv[r] * dinv[c];
    unsigned pos = atomicAdd(&cursor[c], 1u);
    csr[pos] = ((unsigned long long)__float_as_uint(cf) << 32) | (unsigned)(r & 1023);
  }
}

// Aggregate x over normalized adjacency -> y bf16 hi/lo planes.
// Block = (graph g, 16-col chunk): halves edge-visits vs 8-col version.
// 16-lane groups; each group runs TWO dest segments concurrently (d, d+32)
// with a branch-free predicated loop (8 csr loads in flight, no divergence
// between the pair). xs stride-17 kills bank conflicts.
__global__ __launch_bounds__(256, 2) void k_aggx(const float* __restrict__ x,
    const unsigned long long* __restrict__ csr, const unsigned* __restrict__ rstart,
    const float* __restrict__ dinv, unsigned short* __restrict__ yhi,
    unsigned short* __restrict__ ylo, int gbase) {
  __shared__ float xs[1024 * 17];   // 68 KB
  __shared__ unsigned rp[1025];
  __shared__ float dv2[1024];
  int bid = blockIdx.x;
  int g  = bid & 31;                // graph g -> XCD g%8 (L2 locality)
  int cc = bid >> 5;                // 16 chunks of 16 columns
  int gg = gbase + g;
  int c0 = cc * 16;
  int t = threadIdx.x;
  int nbase = gg << 10;
  for (int i = t; i < 1024; i += 256) {
    rp[i] = rstart[nbase + i];
    float dv = dinv[nbase + i];
    dv2[i] = dv * dv;
  }
  if (t == 0) rp[1024] = rstart[nbase + 1024];
  // stage x[:, c0:c0+16] via float4 loads
#pragma unroll
  for (int s = 0; s < 16; ++s) {
    int i = t + s * 256;            // float4-slot: row = i>>2, quad = i&3
    int row = i >> 2, q = (i & 3) * 4;
    float4 v = *(const float4*)&x[(nbase + row) * 256 + c0 + q];
    float* d = &xs[row * 17 + q];
    d[0] = v.x; d[1] = v.y; d[2] = v.z; d[3] = v.w;
  }
  __syncthreads();
  int j = t & 15, grp = t >> 4;     // 16 groups of 16 lanes
  int dbase = grp * 64;             // group owns dests [dbase, dbase+64)
  for (int dd = 0; dd < 32; ++dd) {
    int d0 = dbase + dd, d1 = d0 + 32;
    unsigned p0 = rp[d0], q0 = rp[d0 + 1];
    unsigned p1 = rp[d1], q1 = rp[d1 + 1];
    int L0 = (int)(q0 - p0), L1 = (int)(q1 - p1);
    int L = L0 > L1 ? L0 : L1;
    float a0 = dv2[d0] * xs[d0 * 17 + j];
    float a1 = dv2[d1] * xs[d1 * 17 + j];
    for (int k = 0; k < L; k += 4) {
      unsigned long long cv0[4], cv1[4];
#pragma unroll
      for (int u = 0; u < 4; ++u) {
        int kk = k + u;
        cv0[u] = csr[kk < L0 ? p0 + kk : 0u];
        cv1[u] = csr[kk < L1 ? p1 + kk : 0u];
      }
#pragma unroll
      for (int u = 0; u < 4; ++u) {
        int kk = k + u;
        float f0 = kk < L0 ? __uint_as_float((unsigned)(cv0[u] >> 32)) : 0.0f;
        float f1 = kk < L1 ? __uint_as_float((unsigned)(cv1[u] >> 32)) : 0.0f;
        a0 += f0 * xs[(unsigned)(cv0[u] & 1023) * 17 + j];
        a1 += f1 * xs[(unsigned)(cv1[u] & 1023) * 17 + j];
      }
    }
    int i0 = ((g << 10) + d0) * 256 + c0 + j;
    int i1 = ((g << 10) + d1) * 256 + c0 + j;
    unsigned short h0 = bf16rne(a0), h1 = bf16rne(a1);
    yhi[i0] = h0;
    ylo[i0] = bf16rne(a0 - __uint_as_float((unsigned)h0 << 16));
    yhi[i1] = h1;
    ylo[i1] = bf16rne(a1 - __uint_as_float((unsigned)h1 << 16));
  }
}

// MFMA GEMM: h = y(32768x256) @ W1(256x512) via bf16 hi/lo 3-product split,
// fused +b1 -> LeakyReLU -> dot W2 -> atomic z.  128x128 tile, 4 waves (64x64).
__global__ __launch_bounds__(256, 2) void k_gemm(
    const unsigned short* __restrict__ yhi, const unsigned short* __restrict__ ylo,
    const unsigned short* __restrict__ w1hi, const unsigned short* __restrict__ w1lo,
    const float* __restrict__ b1, const float* __restrict__ W2,
    float* __restrict__ z, int node_base) {
  __shared__ unsigned short Ah_s[128 * 40], Al_s[128 * 40];  // [row][40] ushort, 80B stride
  __shared__ unsigned short Bh_s[128 * 40], Bl_s[128 * 40];  // [col][40]
  int bx = blockIdx.x & 3, by = blockIdx.x >> 2;
  int r0 = by * 128, c0 = bx * 128;
  int t = threadIdx.x;
  int lane = t & 63, wid = t >> 6;
  int wr = wid >> 1, wc = wid & 1;         // wave tile origin (wr*64, wc*64)
  int lr = lane & 15, hg = lane >> 4;
  f32x4 acc[4][4];
#pragma unroll
  for (int m = 0; m < 4; ++m)
#pragma unroll
    for (int n = 0; n < 4; ++n)
      acc[m][n] = (f32x4){0.0f, 0.0f, 0.0f, 0.0f};
  int rr = t >> 2, kq = (t & 3) * 8;       // staging: rows rr, rr+64; 8-elem k-chunk
  for (int kt = 0; kt < 256; kt += 32) {
    us8 va0 = *(const us8*)&yhi[(r0 + rr) * 256 + kt + kq];
    us8 va1 = *(const us8*)&yhi[(r0 + rr + 64) * 256 + kt + kq];
    us8 vb0 = *(const us8*)&ylo[(r0 + rr) * 256 + kt + kq];
    us8 vb1 = *(const us8*)&ylo[(r0 + rr + 64) * 256 + kt + kq];
    us8 vc0 = *(const us8*)&w1hi[(c0 + rr) * 256 + kt + kq];
    us8 vc1 = *(const us8*)&w1hi[(c0 + rr + 64) * 256 + kt + kq];
    us8 vd0 = *(const us8*)&w1lo[(c0 + rr) * 256 + kt + kq];
    us8 vd1 = *(const us8*)&w1lo[(c0 + rr + 64) * 256 + kt + kq];
    __syncthreads();                        // prev-step frag reads complete
    *(us8*)&Ah_s[rr * 40 + kq] = va0;  *(us8*)&Ah_s[(rr + 64) * 40 + kq] = va1;
    *(us8*)&Al_s[rr * 40 + kq] = vb0;  *(us8*)&Al_s[(rr + 64) * 40 + kq] = vb1;
    *(us8*)&Bh_s[rr * 40 + kq] = vc0;  *(us8*)&Bh_s[(rr + 64) * 40 + kq] = vc1;
    *(us8*)&Bl_s[rr * 40 + kq] = vd0;  *(us8*)&Bl_s[(rr + 64) * 40 + kq] = vd1;
    __syncthreads();
    bfrag Ah[4], Al[4], Bh[4], Bl[4];
#pragma unroll
    for (int m = 0; m < 4; ++m) {
      int ra = (wr * 64 + m * 16 + lr) * 40 + hg * 8;
      Ah[m] = *(const bfrag*)&Ah_s[ra];
      Al[m] = *(const bfrag*)&Al_s[ra];
      int rb = (wc * 64 + m * 16 + lr) * 40 + hg * 8;
      Bh[m] = *(const bfrag*)&Bh_s[rb];
      Bl[m] = *(const bfrag*)&Bl_s[rb];
    }
#pragma unroll
    for (int m = 0; m < 4; ++m)
#pragma unroll
      for (int n = 0; n < 4; ++n) {
        acc[m][n] = __builtin_amdgcn_mfma_f32_16x16x32_bf16(Ah[m], Bh[n], acc[m][n], 0, 0, 0);
        acc[m][n] = __builtin_amdgcn_mfma_f32_16x16x32_bf16(Ah[m], Bl[n], acc[m][n], 0, 0, 0);
        acc[m][n] = __builtin_amdgcn_mfma_f32_16x16x32_bf16(Al[m], Bh[n], acc[m][n], 0, 0, 0);
      }
  }
  // epilogue: +b1, LeakyReLU, dot W2, reduce over the 16 col-lanes, atomic z
  float p[4][4];
#pragma unroll
  for (int m = 0; m < 4; ++m)
#pragma unroll
    for (int i = 0; i < 4; ++i) p[m][i] = 0.0f;
#pragma unroll
  for (int n = 0; n < 4; ++n) {
    int col = c0 + wc * 64 + n * 16 + lr;
    float b1v = b1[col], w2v = W2[col];
#pragma unroll
    for (int m = 0; m < 4; ++m)
#pragma unroll
      for (int i = 0; i < 4; ++i) {
        float v = acc[m][n][i] + b1v;
        v = v > 0.0f ? v : 0.01f * v;
        p[m][i] += v * w2v;
      }
  }
#pragma unroll
  for (int off = 8; off > 0; off >>= 1)
#pragma unroll
    for (int m = 0; m < 4; ++m)
#pragma unroll
      for (int i = 0; i < 4; ++i)
        p[m][i] += __shfl_xor(p[m][i], off, 16);
  if (lr == 0) {
    int rbase = node_base + r0 + wr * 64 + hg * 4;
#pragma unroll
    for (int m = 0; m < 4; ++m)
#pragma unroll
      for (int i = 0; i < 4; ++i)
        unsafeAtomicAdd(&z[rbase + m * 16 + i], p[m][i]);
  }
}

// score[n] = b2 + dinv[n]^2*z[n] + sum_{e in seg(n)} coef[e]*z[global_row]
// Also initializes mask[n] = -1 (fused, saves a launch).
__global__ void k_score(const unsigned long long* __restrict__ csr,
                        const unsigned* __restrict__ rstart,
                        const float* __restrict__ dinv, const float* __restrict__ z,
                        const float* __restrict__ b2, float* __restrict__ score,
                        int* __restrict__ mask) {
  int n = blockIdx.x * 256 + threadIdx.x;
  if (n >= NN) return;
  mask[n] = -1;
  int nb = n & ~1023;
  float dv = dinv[n];
  float a = b2[0] + dv * dv * z[n];
  unsigned s = rstart[n], epos = rstart[n + 1];
  for (unsigned e = s; e < epos; ++e) {
    unsigned long long p = csr[e];
    a += __uint_as_float((unsigned)(p >> 32)) * z[nb + (unsigned)(p & 1023)];
  }
  score[n] = a;
}

__device__ void bitonic(unsigned long long* keys, int n, int t, int nt) {
  for (int k = 2; k <= n; k <<= 1)
    for (int jj = k >> 1; jj > 0; jj >>= 1) {
      __syncthreads();
      for (int i = t; i < n; i += nt) {
        int ixj = i ^ jj;
        if (ixj > i) {
          unsigned long long a = keys[i], c = keys[ixj];
          bool up = ((i & k) == 0);
          if ((a > c) == up) { keys[i] = c; keys[ixj] = a; }
        }
      }
    }
  __syncthreads();
}

__global__ __launch_bounds__(256) void k_topk(const float* __restrict__ score,
                                              int* __restrict__ mask,
                                              float* __restrict__ out) {
  __shared__ unsigned long long keys[1024];
  int b = blockIdx.x, t = threadIdx.x;
  int base = b << 10;
  if (t < 64) {
    float v = score[base + t];
    keys[t] = ((unsigned long long)(~monof(v)) << 32) | (unsigned)t;
    out[O6 + b * 64 + t] = v;
    out[O7 + b * 64 + t] = (float)b;
  }
  __syncthreads();
  bitonic(keys, 64, t, 256);
  if (t < 3) {
    int idx = (int)(keys[t] & 0xFFFFFFFFull);
    int node = base + idx;
    int pos = b * 3 + t;
    mask[node] = pos;
    out[O4 + pos] = (float)node;
    out[O5 + pos] = score[node];
    out[O3 + pos] = (float)b;
  }
  __syncthreads();
  for (int i = t; i < 1024; i += 256) {
    if (i < 960) {
      float v = score[base + 64 + i];
      keys[i] = ((unsigned long long)(~monof(v)) << 32) | (unsigned)i;
    } else {
      keys[i] = 0xFFFFFFFFFFFFFFFFull;
    }
  }
  __syncthreads();
  bitonic(keys, 1024, t, 256);
  for (int r = t; r < 480; r += 256) {
    int idx = (int)(keys[r] & 0xFFFFFFFFull);
    int node = base + 64 + idx;
    int pos = 192 + b * 480 + r;
    mask[node] = pos;
    out[O4 + pos] = (float)node;
    out[O5 + pos] = score[node];
    out[O3 + pos] = (float)b;
  }
}

__global__ void k_edges(const int* __restrict__ ei, const float* __restrict__ w,
                        const int* __restrict__ mask, float* __restrict__ out) {
  int e = blockIdx.x * 256 + threadIdx.x;
  if (e >= NE) return;
  int nr = mask[ei[e]];
  int nc = mask[ei[NE + e]];
  bool keep = (nr >= 0) && (nc >= 0);
  out[O1 + e]      = keep ? (float)nr : -1.0f;
  out[O1 + NE + e] = keep ? (float)nc : -1.0f;
  out[O2 + e]      = keep ? w[e] : 0.0f;
  out[O8 + e]      = keep ? 1.0f : 0.0f;
}

__global__ void k_xout(const float* __restrict__ x, const float* __restrict__ permF,
                       const float* __restrict__ scoreP, float* __restrict__ out) {
  int i = blockIdx.x;
  int node = (int)permF[i];
  float s = scoreP[i];
  const float4* xr = (const float4*)&x[node * 256];
  float4* o = (float4*)&out[i * 256];
  float4 v = xr[threadIdx.x];
  o[threadIdx.x] = make_float4(v.x * s, v.y * s, v.z * s, v.w * s);
}

extern "C" void kernel_launch(void* const* d_in, const int* in_sizes, int n_in,
                              void* d_out, int out_size, void* d_ws, size_t ws_size,
                              hipStream_t stream) {
  (void)in_sizes; (void)n_in; (void)out_size; (void)d_ws; (void)ws_size;
  const float* x  = (const float*)d_in[0];
  const int*   ei = (const int*)d_in[1];
  const float* w  = (const float*)d_in[2];
  const float* W1 = (const float*)d_in[4];
  const float* b1 = (const float*)d_in[5];
  const float* W2 = (const float*)d_in[6];
  const float* b2 = (const float*)d_in[7];
  float* out    = (float*)d_out;
  unsigned short* yhi = (unsigned short*)out;                  // [32768*256] per chunk
  unsigned short* ylo = (unsigned short*)(out + YLO_OFF);
  unsigned long long* csr = (unsigned long long*)(out + CSR_OFF);
  float* dinv   = out + DINV_OFF;
  float* z      = out + Z_OFF;
  unsigned* cnt    = (unsigned*)(out + CNT_OFF);
  unsigned* rstart = (unsigned*)(out + RSTART_OFF);
  unsigned* cursor = (unsigned*)(out + CURSOR_OFF);
  float* wsum   = out + WSUM_OFF;
  unsigned short* w1hi = (unsigned short*)(out + CNT_OFF);     // reuse cnt after k_prefix
  unsigned short* w1lo = (unsigned short*)(out + WSUM_OFF);    // reuse wsum after k_prefix
  float* score  = out + SCORE_OFF;
  int*   mask   = (int*)d_out;

  k_zero<<<256, 256, 0, stream>>>(cnt, wsum, z);
  k_hist<<<2048, 256, 0, stream>>>(ei, w, cnt, wsum);
  k_prefix<<<64, 256, 0, stream>>>(cnt, wsum, rstart, cursor, dinv);
  k_w1t<<<32, 256, 0, stream>>>(W1, w1hi, w1lo);               // cnt/wsum dead now
  k_scatter<<<2048, 256, 0, stream>>>(ei, w, dinv, cursor, csr);
  for (int ch = 0; ch < 2; ++ch) {
    k_aggx<<<512, 256, 0, stream>>>(x, csr, rstart, dinv, yhi, ylo, ch * 32);
    k_gemm<<<1024, 256, 0, stream>>>(yhi, ylo, w1hi, w1lo, b1, W2, z, ch * 32768);
  }
  k_score<<<256, 256, 0, stream>>>(csr, rstart, dinv, z, b2, score, mask);
  k_topk<<<64, 256, 0, stream>>>(score, mask, out);
  k_edges<<<2048, 256, 0, stream>>>(ei, w, mask, out);
  k_xout<<<30912, 64, 0, stream>>>(x, out + O4, out + O5, out);
}